// Round 2
// baseline (816.363 us; speedup 1.0000x reference)
//
#include <hip/hip_runtime.h>
#include <cstdint>
#include <cstddef>

#define NN 100000
#define NE 1200000

// ---------- small utility kernels ----------
__global__ void fill_kernel(float* __restrict__ p, float v, int n) {
    int i = blockIdx.x * blockDim.x + threadIdx.x;
    if (i < n) p[i] = v;
}

__global__ void degree_kernel(const int* __restrict__ ei, float* __restrict__ deg, int E) {
    int stride = gridDim.x * blockDim.x;
    for (int e = blockIdx.x * blockDim.x + threadIdx.x; e < E; e += stride) {
        int d = ei[E + e];   // row 1 = dst
        atomicAdd(&deg[d], 1.0f);
    }
}

__global__ void rsqrt_kernel(float* __restrict__ deg, int n) {
    int i = blockIdx.x * blockDim.x + threadIdx.x;
    if (i < n) deg[i] = rsqrtf(deg[i]);   // deg >= 1 always (self-loop)
}

// ---------- dense GEMM: C[n,64] = A[n,K] @ W[K,64] ----------
// blockDim = (64,4); each block computes 32 rows. W staged in LDS (<=32KB).
template <int K>
__global__ void gemm_nodes(const float* __restrict__ A, const float* __restrict__ W,
                           float* __restrict__ C, int n) {
    __shared__ float sW[K * 64];
    for (int i = threadIdx.x + threadIdx.y * 64; i < K * 64; i += 256) sW[i] = W[i];
    __syncthreads();
    const int col = threadIdx.x;
    for (int r = 0; r < 8; ++r) {
        int row = blockIdx.x * 32 + threadIdx.y + r * 4;
        if (row < n) {
            const float* a = A + (size_t)row * K;
            float acc = 0.0f;
#pragma unroll 8
            for (int k = 0; k < K; ++k) acc = fmaf(a[k], sW[k * 64 + col], acc);
            C[(size_t)row * 64 + col] = acc;
        }
    }
}

// ---------- edge scatter: one wave (64 lanes) per edge, lane = feature col ----------
__global__ void scatter_kernel(const int* __restrict__ ei,
                               const float* __restrict__ hw,
                               const float* __restrict__ dis,
                               float* __restrict__ agg, int E) {
    int gtid = blockIdx.x * blockDim.x + threadIdx.x;
    int wave = gtid >> 6;
    int lane = threadIdx.x & 63;
    int nwaves = (gridDim.x * blockDim.x) >> 6;
    for (int e = wave; e < E; e += nwaves) {
        int s = ei[e];
        int d = ei[E + e];
        float nrm = dis[s] * dis[d];
        float v = hw[(size_t)s * 64 + lane] * nrm;
        atomicAdd(&agg[(size_t)d * 64 + lane], v);
    }
}

// ---------- self-loop + bias + relu: agg = relu(agg + hw*dis^2 + b) ----------
__global__ void finalize_kernel(float* __restrict__ agg, const float* __restrict__ hw,
                                const float* __restrict__ dis, const float* __restrict__ b,
                                int n) {
    int i = blockIdx.x * blockDim.x + threadIdx.x;
    if (i < n * 64) {
        int node = i >> 6;
        int col = i & 63;
        float di = dis[node];
        float v = agg[i] + hw[i] * di * di + b[col];
        agg[i] = v > 0.0f ? v : 0.0f;
    }
}

extern "C" void kernel_launch(void* const* d_in, const int* in_sizes, int n_in,
                              void* d_out, int out_size, void* d_ws, size_t ws_size,
                              hipStream_t stream) {
    const float* x  = (const float*)d_in[0];
    const int*   ei = (const int*)d_in[1];   // harness passes integer inputs as int32; [2, E] flat
    const float* W1 = (const float*)d_in[2];
    const float* b1 = (const float*)d_in[3];
    const float* W2 = (const float*)d_in[4];
    const float* b2 = (const float*)d_in[5];
    float* out = (float*)d_out;

    const int N = NN, E = NE;
    char* ws = (char*)d_ws;
    float* dis  = (float*)ws;                 // N floats (400KB region, pad to 512KB)
    float* bufA = (float*)(ws + (1 << 19));   // N*64 floats (25.6MB) — hw scratch

    const size_t featBytes = (size_t)N * 64 * sizeof(float);
    dim3 gblk(64, 4);

    // --- degree / normalization ---
    fill_kernel<<<(N + 255) / 256, 256, 0, stream>>>(dis, 1.0f, N);  // self-loop contributes 1
    degree_kernel<<<2048, 256, 0, stream>>>(ei, dis, E);
    rsqrt_kernel<<<(N + 255) / 256, 256, 0, stream>>>(dis, N);

    // --- layer 1: h = relu(scatter(norm * (x@W1)) + selfloop + b1) ---
    // hw1 -> bufA; aggregate into d_out (used as h buffer)
    gemm_nodes<128><<<(N + 31) / 32, gblk, 0, stream>>>(x, W1, bufA, N);
    hipMemsetAsync(out, 0, featBytes, stream);
    scatter_kernel<<<2048, 256, 0, stream>>>(ei, bufA, dis, out, E);
    finalize_kernel<<<(N * 64 + 255) / 256, 256, 0, stream>>>(out, bufA, dis, b1, N);

    // --- layer 2: out = relu(scatter(norm * (h@W2)) + selfloop + b2) ---
    // hw2 -> bufA (reads h from d_out first), then reuse d_out as agg
    gemm_nodes<64><<<(N + 31) / 32, gblk, 0, stream>>>(out, W2, bufA, N);
    hipMemsetAsync(out, 0, featBytes, stream);
    scatter_kernel<<<2048, 256, 0, stream>>>(ei, bufA, dis, out, E);
    finalize_kernel<<<(N * 64 + 255) / 256, 256, 0, stream>>>(out, bufA, dis, b2, N);
}

// Round 3
// 750.810 us; speedup vs baseline: 1.0873x; 1.0873x over previous
//
#include <hip/hip_runtime.h>
#include <cstdint>
#include <cstddef>

#define NN 100000
#define NE 1200000

// ================= CSR build =================
__global__ void count_kernel(const int* __restrict__ ei, int* __restrict__ cnt, int E) {
    int stride = gridDim.x * blockDim.x;
    for (int e = blockIdx.x * blockDim.x + threadIdx.x; e < E; e += stride)
        atomicAdd(&cnt[ei[E + e]], 1);
}

__global__ void dis_kernel(const int* __restrict__ cnt, float* __restrict__ dis, int n) {
    int i = blockIdx.x * blockDim.x + threadIdx.x;
    if (i < n) dis[i] = rsqrtf((float)cnt[i] + 1.0f);   // +1 self-loop
}

// single-block exclusive scan over n counts -> row_ptr[n+1], plus cursor copy
__global__ void scan_kernel(const int* __restrict__ cnt, int* __restrict__ row_ptr,
                            int* __restrict__ cursor, int n) {
    __shared__ int part[1024];
    int t = threadIdx.x;
    int chunk = (n + 1023) / 1024;
    int lo = t * chunk, hi = min(lo + chunk, n);
    int s = 0;
    for (int i = lo; i < hi; i++) s += cnt[i];
    part[t] = s;
    __syncthreads();
    for (int off = 1; off < 1024; off <<= 1) {
        int v = (t >= off) ? part[t - off] : 0;
        __syncthreads();
        part[t] += v;
        __syncthreads();
    }
    int excl = (t == 0) ? 0 : part[t - 1];
    for (int i = lo; i < hi; i++) { int c = cnt[i]; row_ptr[i] = excl; cursor[i] = excl; excl += c; }
    if (t == 1023) row_ptr[n] = part[1023];
}

__global__ void fill_csr(const int* __restrict__ ei, const float* __restrict__ dis,
                         int* __restrict__ cursor, int2* __restrict__ edges, int E) {
    int stride = gridDim.x * blockDim.x;
    for (int e = blockIdx.x * blockDim.x + threadIdx.x; e < E; e += stride) {
        int s = ei[e], d = ei[E + e];
        float nrm = dis[s] * dis[d];
        int pos = atomicAdd(&cursor[d], 1);
        edges[pos] = make_int2(s, __float_as_int(nrm));
    }
}

// ============ aggregation: one wave per node, fused selfloop+bias+relu ============
__global__ void agg_kernel(const int* __restrict__ row_ptr, const int2* __restrict__ edges,
                           const float* __restrict__ hw, const float* __restrict__ dis,
                           const float* __restrict__ b, float* __restrict__ out, int n) {
    int wid = (blockIdx.x * blockDim.x + threadIdx.x) >> 6;
    if (wid >= n) return;
    int lane = threadIdx.x & 63;
    int beg = row_ptr[wid], end = row_ptr[wid + 1];
    float di = dis[wid];
    float acc = hw[(size_t)wid * 64 + lane] * di * di;   // self-loop term
    for (int e = beg; e < end; e++) {
        int2 pr = edges[e];
        acc = fmaf(hw[(size_t)pr.x * 64 + lane], __int_as_float(pr.y), acc);
    }
    float v = acc + b[lane];
    out[(size_t)wid * 64 + lane] = v > 0.f ? v : 0.f;
}

// ============ GEMM: C[n,64] = A[n,K] @ W[K,64], float4 A reads, acc[8] ============
template <int K>
__global__ void gemm_nodes(const float* __restrict__ A, const float* __restrict__ W,
                           float* __restrict__ C, int n) {
    __shared__ float sW[K * 64];
    int tid = threadIdx.x + threadIdx.y * 64;
    for (int i = tid; i < K * 16; i += 256) ((float4*)sW)[i] = ((const float4*)W)[i];
    __syncthreads();
    const int col = threadIdx.x;
    const int row0 = blockIdx.x * 32 + threadIdx.y;   // rows row0 + 4r, n % 32 == 0
    float acc[8] = {0, 0, 0, 0, 0, 0, 0, 0};
    const float4* A4 = (const float4*)A;
    for (int k = 0; k < K; k += 4) {
        float w0 = sW[k * 64 + col], w1 = sW[(k + 1) * 64 + col];
        float w2 = sW[(k + 2) * 64 + col], w3 = sW[(k + 3) * 64 + col];
#pragma unroll
        for (int r = 0; r < 8; r++) {
            float4 a = A4[(size_t)(row0 + r * 4) * (K / 4) + (k / 4)];
            acc[r] = fmaf(a.x, w0, acc[r]);
            acc[r] = fmaf(a.y, w1, acc[r]);
            acc[r] = fmaf(a.z, w2, acc[r]);
            acc[r] = fmaf(a.w, w3, acc[r]);
        }
    }
#pragma unroll
    for (int r = 0; r < 8; r++) C[(size_t)(row0 + r * 4) * 64 + col] = acc[r];
}

// ================= fallback (R2 proven path, small ws) =================
__global__ void fill_kernel(float* __restrict__ p, float v, int n) {
    int i = blockIdx.x * blockDim.x + threadIdx.x;
    if (i < n) p[i] = v;
}
__global__ void degree_kernel(const int* __restrict__ ei, float* __restrict__ deg, int E) {
    int stride = gridDim.x * blockDim.x;
    for (int e = blockIdx.x * blockDim.x + threadIdx.x; e < E; e += stride)
        atomicAdd(&deg[ei[E + e]], 1.0f);
}
__global__ void rsqrt_kernel(float* __restrict__ deg, int n) {
    int i = blockIdx.x * blockDim.x + threadIdx.x;
    if (i < n) deg[i] = rsqrtf(deg[i]);
}
__global__ void scatter_kernel(const int* __restrict__ ei, const float* __restrict__ hw,
                               const float* __restrict__ dis, float* __restrict__ agg, int E) {
    int gtid = blockIdx.x * blockDim.x + threadIdx.x;
    int wave = gtid >> 6, lane = threadIdx.x & 63;
    int nwaves = (gridDim.x * blockDim.x) >> 6;
    for (int e = wave; e < E; e += nwaves) {
        int s = ei[e], d = ei[E + e];
        float v = hw[(size_t)s * 64 + lane] * dis[s] * dis[d];
        atomicAdd(&agg[(size_t)d * 64 + lane], v);
    }
}
__global__ void finalize_kernel(float* __restrict__ agg, const float* __restrict__ hw,
                                const float* __restrict__ dis, const float* __restrict__ b, int n) {
    int i = blockIdx.x * blockDim.x + threadIdx.x;
    if (i < n * 64) {
        int node = i >> 6, col = i & 63;
        float di = dis[node];
        float v = agg[i] + hw[i] * di * di + b[col];
        agg[i] = v > 0.0f ? v : 0.0f;
    }
}

extern "C" void kernel_launch(void* const* d_in, const int* in_sizes, int n_in,
                              void* d_out, int out_size, void* d_ws, size_t ws_size,
                              hipStream_t stream) {
    const float* x  = (const float*)d_in[0];
    const int*   ei = (const int*)d_in[1];   // int32 [2, E] flat
    const float* W1 = (const float*)d_in[2];
    const float* b1 = (const float*)d_in[3];
    const float* W2 = (const float*)d_in[4];
    const float* b2 = (const float*)d_in[5];
    float* out = (float*)d_out;

    const int N = NN, E = NE;
    char* ws = (char*)d_ws;
    dim3 gblk(64, 4);

    if (ws_size >= 38200000u) {
        // ---- CSR path ----
        int*   cnt     = (int*)ws;                       // 0 .. 512K
        int*   row_ptr = (int*)(ws + (1u << 19));        // 512K .. 1M
        int*   cursor  = (int*)(ws + (2u << 19));        // 1M .. 1.5M
        float* dis     = (float*)(ws + (3u << 19));      // 1.5M .. 2M
        int2*  edges   = (int2*)(ws + (4u << 19));       // 2M .. 11.6M (9.6MB)
        float* bufA    = (float*)(ws + 12582912u);       // 12M .. 37.6M

        hipMemsetAsync(cnt, 0, (N + 1) * sizeof(int), stream);
        count_kernel<<<2048, 256, 0, stream>>>(ei, cnt, E);
        dis_kernel<<<(N + 255) / 256, 256, 0, stream>>>(cnt, dis, N);
        scan_kernel<<<1, 1024, 0, stream>>>(cnt, row_ptr, cursor, N);
        fill_csr<<<2048, 256, 0, stream>>>(ei, dis, cursor, edges, E);

        // layer 1: hw1 -> bufA; h -> out
        gemm_nodes<128><<<N / 32, gblk, 0, stream>>>(x, W1, bufA, N);
        agg_kernel<<<(N * 64 + 255) / 256, 256, 0, stream>>>(row_ptr, edges, bufA, dis, b1, out, N);
        // layer 2: hw2 -> bufA; out final
        gemm_nodes<64><<<N / 32, gblk, 0, stream>>>(out, W2, bufA, N);
        agg_kernel<<<(N * 64 + 255) / 256, 256, 0, stream>>>(row_ptr, edges, bufA, dis, b2, out, N);
    } else {
        // ---- fallback: R2 atomic path ----
        float* dis  = (float*)ws;
        float* bufA = (float*)(ws + (1 << 19));
        const size_t featBytes = (size_t)N * 64 * sizeof(float);

        fill_kernel<<<(N + 255) / 256, 256, 0, stream>>>(dis, 1.0f, N);
        degree_kernel<<<2048, 256, 0, stream>>>(ei, dis, E);
        rsqrt_kernel<<<(N + 255) / 256, 256, 0, stream>>>(dis, N);

        gemm_nodes<128><<<N / 32, gblk, 0, stream>>>(x, W1, bufA, N);
        hipMemsetAsync(out, 0, featBytes, stream);
        scatter_kernel<<<2048, 256, 0, stream>>>(ei, bufA, dis, out, E);
        finalize_kernel<<<(N * 64 + 255) / 256, 256, 0, stream>>>(out, bufA, dis, b1, N);

        gemm_nodes<64><<<N / 32, gblk, 0, stream>>>(out, W2, bufA, N);
        hipMemsetAsync(out, 0, featBytes, stream);
        scatter_kernel<<<2048, 256, 0, stream>>>(ei, bufA, dis, out, E);
        finalize_kernel<<<(N * 64 + 255) / 256, 256, 0, stream>>>(out, bufA, dis, b2, N);
    }
}

// Round 4
// 536.527 us; speedup vs baseline: 1.5216x; 1.3994x over previous
//
#include <hip/hip_runtime.h>
#include <cstdint>
#include <cstddef>

#define NN 100000
#define NE 1200000

// ================= CSR build =================
__global__ void count_kernel(const int* __restrict__ ei, int* __restrict__ cnt, int E) {
    int stride = gridDim.x * blockDim.x;
    for (int e = blockIdx.x * blockDim.x + threadIdx.x; e < E; e += stride)
        atomicAdd(&cnt[ei[E + e]], 1);
}

__global__ void dis_kernel(const int* __restrict__ cnt, float* __restrict__ dis, int n) {
    int i = blockIdx.x * blockDim.x + threadIdx.x;
    if (i < n) dis[i] = rsqrtf((float)cnt[i] + 1.0f);   // +1 self-loop
}

// ---- 3-phase multi-block exclusive scan (1024 counts per block, 256 thr) ----
__global__ void scan_phase1(const int* __restrict__ cnt, int* __restrict__ blkSum, int n) {
    __shared__ int red[256];
    int base = blockIdx.x * 1024, t = threadIdx.x;
    int s = 0;
#pragma unroll
    for (int j = 0; j < 4; j++) {
        int i = base + t * 4 + j;
        if (i < n) s += cnt[i];
    }
    red[t] = s;
    __syncthreads();
    for (int off = 128; off > 0; off >>= 1) {
        if (t < off) red[t] += red[t + off];
        __syncthreads();
    }
    if (t == 0) blkSum[blockIdx.x] = red[0];
}

// single tiny block: exclusive-scan the <=128 block sums; also writes row_ptr[n]=total
__global__ void scan_phase2(int* __restrict__ blkSum, int* __restrict__ row_ptr, int nblk, int n) {
    __shared__ int sh[128];
    int t = threadIdx.x;
    int v = (t < nblk) ? blkSum[t] : 0;
    sh[t] = v;
    __syncthreads();
    for (int off = 1; off < 128; off <<= 1) {
        int u = (t >= off) ? sh[t - off] : 0;
        __syncthreads();
        sh[t] += u;
        __syncthreads();
    }
    if (t < nblk) blkSum[t] = (t == 0) ? 0 : sh[t - 1];
    if (t == 0) row_ptr[n] = sh[127];
}

__global__ void scan_phase3(const int* __restrict__ cnt, const int* __restrict__ blkSum,
                            int* __restrict__ row_ptr, int* __restrict__ cursor, int n) {
    __shared__ int sh[256];
    int base = blockIdx.x * 1024, t = threadIdx.x;
    int idx = base + t * 4;
    int c[4];
    int s = 0;
#pragma unroll
    for (int j = 0; j < 4; j++) {
        int i = idx + j;
        c[j] = (i < n) ? cnt[i] : 0;
        s += c[j];
    }
    sh[t] = s;
    __syncthreads();
    for (int off = 1; off < 256; off <<= 1) {
        int u = (t >= off) ? sh[t - off] : 0;
        __syncthreads();
        sh[t] += u;
        __syncthreads();
    }
    int excl = blkSum[blockIdx.x] + ((t == 0) ? 0 : sh[t - 1]);
#pragma unroll
    for (int j = 0; j < 4; j++) {
        int i = idx + j;
        if (i < n) { row_ptr[i] = excl; cursor[i] = excl; }
        excl += c[j];
    }
}

__global__ void fill_csr(const int* __restrict__ ei, const float* __restrict__ dis,
                         int* __restrict__ cursor, int2* __restrict__ edges, int E) {
    int stride = gridDim.x * blockDim.x;
    for (int e = blockIdx.x * blockDim.x + threadIdx.x; e < E; e += stride) {
        int s = ei[e], d = ei[E + e];
        float nrm = dis[s] * dis[d];
        int pos = atomicAdd(&cursor[d], 1);
        edges[pos] = make_int2(s, __float_as_int(nrm));
    }
}

// ============ aggregation: one wave per node, fused selfloop+bias+relu ============
__global__ void agg_kernel(const int* __restrict__ row_ptr, const int2* __restrict__ edges,
                           const float* __restrict__ hw, const float* __restrict__ dis,
                           const float* __restrict__ b, float* __restrict__ out, int n) {
    int wid = (blockIdx.x * blockDim.x + threadIdx.x) >> 6;
    if (wid >= n) return;
    int lane = threadIdx.x & 63;
    int beg = row_ptr[wid], end = row_ptr[wid + 1];
    float di = dis[wid];
    float acc = hw[(size_t)wid * 64 + lane] * di * di;   // self-loop term
    for (int e = beg; e < end; e++) {
        int2 pr = edges[e];
        acc = fmaf(hw[(size_t)pr.x * 64 + lane], __int_as_float(pr.y), acc);
    }
    float v = acc + b[lane];
    out[(size_t)wid * 64 + lane] = v > 0.f ? v : 0.f;
}

// ============ GEMM: C[n,64] = A[n,K] @ W[K,64], float4 A reads, acc[8] ============
template <int K>
__global__ void gemm_nodes(const float* __restrict__ A, const float* __restrict__ W,
                           float* __restrict__ C, int n) {
    __shared__ float sW[K * 64];
    int tid = threadIdx.x + threadIdx.y * 64;
    for (int i = tid; i < K * 16; i += 256) ((float4*)sW)[i] = ((const float4*)W)[i];
    __syncthreads();
    const int col = threadIdx.x;
    const int row0 = blockIdx.x * 32 + threadIdx.y;   // rows row0 + 4r, n % 32 == 0
    float acc[8] = {0, 0, 0, 0, 0, 0, 0, 0};
    const float4* A4 = (const float4*)A;
    for (int k = 0; k < K; k += 4) {
        float w0 = sW[k * 64 + col], w1 = sW[(k + 1) * 64 + col];
        float w2 = sW[(k + 2) * 64 + col], w3 = sW[(k + 3) * 64 + col];
#pragma unroll
        for (int r = 0; r < 8; r++) {
            float4 a = A4[(size_t)(row0 + r * 4) * (K / 4) + (k / 4)];
            acc[r] = fmaf(a.x, w0, acc[r]);
            acc[r] = fmaf(a.y, w1, acc[r]);
            acc[r] = fmaf(a.z, w2, acc[r]);
            acc[r] = fmaf(a.w, w3, acc[r]);
        }
    }
#pragma unroll
    for (int r = 0; r < 8; r++) C[(size_t)(row0 + r * 4) * 64 + col] = acc[r];
}

// ================= fallback (R2 proven path, small ws) =================
__global__ void fill_kernel(float* __restrict__ p, float v, int n) {
    int i = blockIdx.x * blockDim.x + threadIdx.x;
    if (i < n) p[i] = v;
}
__global__ void degree_kernel(const int* __restrict__ ei, float* __restrict__ deg, int E) {
    int stride = gridDim.x * blockDim.x;
    for (int e = blockIdx.x * blockDim.x + threadIdx.x; e < E; e += stride)
        atomicAdd(&deg[ei[E + e]], 1.0f);
}
__global__ void rsqrt_kernel(float* __restrict__ deg, int n) {
    int i = blockIdx.x * blockDim.x + threadIdx.x;
    if (i < n) deg[i] = rsqrtf(deg[i]);
}
__global__ void scatter_kernel(const int* __restrict__ ei, const float* __restrict__ hw,
                               const float* __restrict__ dis, float* __restrict__ agg, int E) {
    int gtid = blockIdx.x * blockDim.x + threadIdx.x;
    int wave = gtid >> 6, lane = threadIdx.x & 63;
    int nwaves = (gridDim.x * blockDim.x) >> 6;
    for (int e = wave; e < E; e += nwaves) {
        int s = ei[e], d = ei[E + e];
        float v = hw[(size_t)s * 64 + lane] * dis[s] * dis[d];
        atomicAdd(&agg[(size_t)d * 64 + lane], v);
    }
}
__global__ void finalize_kernel(float* __restrict__ agg, const float* __restrict__ hw,
                                const float* __restrict__ dis, const float* __restrict__ b, int n) {
    int i = blockIdx.x * blockDim.x + threadIdx.x;
    if (i < n * 64) {
        int node = i >> 6, col = i & 63;
        float di = dis[node];
        float v = agg[i] + hw[i] * di * di + b[col];
        agg[i] = v > 0.0f ? v : 0.0f;
    }
}

extern "C" void kernel_launch(void* const* d_in, const int* in_sizes, int n_in,
                              void* d_out, int out_size, void* d_ws, size_t ws_size,
                              hipStream_t stream) {
    const float* x  = (const float*)d_in[0];
    const int*   ei = (const int*)d_in[1];   // int32 [2, E] flat
    const float* W1 = (const float*)d_in[2];
    const float* b1 = (const float*)d_in[3];
    const float* W2 = (const float*)d_in[4];
    const float* b2 = (const float*)d_in[5];
    float* out = (float*)d_out;

    const int N = NN, E = NE;
    char* ws = (char*)d_ws;
    dim3 gblk(64, 4);

    if (ws_size >= 38200000u) {
        // ---- CSR path ----
        int*   cnt     = (int*)ws;                       // 0 .. 512K
        int*   row_ptr = (int*)(ws + (1u << 19));        // 512K .. 1M
        int*   cursor  = (int*)(ws + (2u << 19));        // 1M .. 1.5M
        float* dis     = (float*)(ws + (3u << 19));      // 1.5M .. 2M (first 512B reused as blkSum)
        int2*  edges   = (int2*)(ws + (4u << 19));       // 2M .. 11.6M (9.6MB)
        float* bufA    = (float*)(ws + 12582912u);       // 12M .. 37.6M
        int*   blkSum  = cursor + ((NN + 127) & ~127) + 256;  // tail of cursor region (98 ints)

        const int nblk = (N + 1023) / 1024;  // 98

        hipMemsetAsync(cnt, 0, (N + 1) * sizeof(int), stream);
        count_kernel<<<2048, 256, 0, stream>>>(ei, cnt, E);
        dis_kernel<<<(N + 255) / 256, 256, 0, stream>>>(cnt, dis, N);
        scan_phase1<<<nblk, 256, 0, stream>>>(cnt, blkSum, N);
        scan_phase2<<<1, 128, 0, stream>>>(blkSum, row_ptr, nblk, N);
        scan_phase3<<<nblk, 256, 0, stream>>>(cnt, blkSum, row_ptr, cursor, N);
        fill_csr<<<2048, 256, 0, stream>>>(ei, dis, cursor, edges, E);

        // layer 1: hw1 -> bufA; h -> out
        gemm_nodes<128><<<N / 32, gblk, 0, stream>>>(x, W1, bufA, N);
        agg_kernel<<<(N * 64 + 255) / 256, 256, 0, stream>>>(row_ptr, edges, bufA, dis, b1, out, N);
        // layer 2: hw2 -> bufA; out final
        gemm_nodes<64><<<N / 32, gblk, 0, stream>>>(out, W2, bufA, N);
        agg_kernel<<<(N * 64 + 255) / 256, 256, 0, stream>>>(row_ptr, edges, bufA, dis, b2, out, N);
    } else {
        // ---- fallback: R2 atomic path ----
        float* dis  = (float*)ws;
        float* bufA = (float*)(ws + (1 << 19));
        const size_t featBytes = (size_t)N * 64 * sizeof(float);

        fill_kernel<<<(N + 255) / 256, 256, 0, stream>>>(dis, 1.0f, N);
        degree_kernel<<<2048, 256, 0, stream>>>(ei, dis, E);
        rsqrt_kernel<<<(N + 255) / 256, 256, 0, stream>>>(dis, N);

        gemm_nodes<128><<<N / 32, gblk, 0, stream>>>(x, W1, bufA, N);
        hipMemsetAsync(out, 0, featBytes, stream);
        scatter_kernel<<<2048, 256, 0, stream>>>(ei, bufA, dis, out, E);
        finalize_kernel<<<(N * 64 + 255) / 256, 256, 0, stream>>>(out, bufA, dis, b1, N);

        gemm_nodes<64><<<N / 32, gblk, 0, stream>>>(out, W2, bufA, N);
        hipMemsetAsync(out, 0, featBytes, stream);
        scatter_kernel<<<2048, 256, 0, stream>>>(ei, bufA, dis, out, E);
        finalize_kernel<<<(N * 64 + 255) / 256, 256, 0, stream>>>(out, bufA, dis, b2, N);
    }
}

// Round 5
// 342.648 us; speedup vs baseline: 2.3825x; 1.5658x over previous
//
#include <hip/hip_runtime.h>
#include <cstdint>
#include <cstddef>

#define NN 100000
#define NE 1200000

// ================= CSR build =================
__global__ void count_kernel(const int* __restrict__ ei, int* __restrict__ cnt, int E) {
    int stride = gridDim.x * blockDim.x;
    for (int e = blockIdx.x * blockDim.x + threadIdx.x; e < E; e += stride)
        atomicAdd(&cnt[ei[E + e]], 1);
}

__global__ void dis_kernel(const int* __restrict__ cnt, float* __restrict__ dis, int n) {
    int i = blockIdx.x * blockDim.x + threadIdx.x;
    if (i < n) dis[i] = rsqrtf((float)cnt[i] + 1.0f);   // +1 self-loop
}

// ---- 3-phase multi-block exclusive scan (1024 counts per block, 256 thr) ----
__global__ void scan_phase1(const int* __restrict__ cnt, int* __restrict__ blkSum, int n) {
    __shared__ int red[256];
    int base = blockIdx.x * 1024, t = threadIdx.x;
    int s = 0;
#pragma unroll
    for (int j = 0; j < 4; j++) {
        int i = base + t * 4 + j;
        if (i < n) s += cnt[i];
    }
    red[t] = s;
    __syncthreads();
    for (int off = 128; off > 0; off >>= 1) {
        if (t < off) red[t] += red[t + off];
        __syncthreads();
    }
    if (t == 0) blkSum[blockIdx.x] = red[0];
}

__global__ void scan_phase2(int* __restrict__ blkSum, int* __restrict__ row_ptr, int nblk, int n) {
    __shared__ int sh[128];
    int t = threadIdx.x;
    int v = (t < nblk) ? blkSum[t] : 0;
    sh[t] = v;
    __syncthreads();
    for (int off = 1; off < 128; off <<= 1) {
        int u = (t >= off) ? sh[t - off] : 0;
        __syncthreads();
        sh[t] += u;
        __syncthreads();
    }
    if (t < nblk) blkSum[t] = (t == 0) ? 0 : sh[t - 1];
    if (t == 0) row_ptr[n] = sh[127];
}

__global__ void scan_phase3(const int* __restrict__ cnt, const int* __restrict__ blkSum,
                            int* __restrict__ row_ptr, int* __restrict__ cursor, int n) {
    __shared__ int sh[256];
    int base = blockIdx.x * 1024, t = threadIdx.x;
    int idx = base + t * 4;
    int c[4];
    int s = 0;
#pragma unroll
    for (int j = 0; j < 4; j++) {
        int i = idx + j;
        c[j] = (i < n) ? cnt[i] : 0;
        s += c[j];
    }
    sh[t] = s;
    __syncthreads();
    for (int off = 1; off < 256; off <<= 1) {
        int u = (t >= off) ? sh[t - off] : 0;
        __syncthreads();
        sh[t] += u;
        __syncthreads();
    }
    int excl = blkSum[blockIdx.x] + ((t == 0) ? 0 : sh[t - 1]);
#pragma unroll
    for (int j = 0; j < 4; j++) {
        int i = idx + j;
        if (i < n) { row_ptr[i] = excl; cursor[i] = excl; }
        excl += c[j];
    }
}

__global__ void fill_csr(const int* __restrict__ ei, const float* __restrict__ dis,
                         int* __restrict__ cursor, int2* __restrict__ edges, int E) {
    int stride = gridDim.x * blockDim.x;
    for (int e = blockIdx.x * blockDim.x + threadIdx.x; e < E; e += stride) {
        int s = ei[e], d = ei[E + e];
        float nrm = dis[s] * dis[d];
        int pos = atomicAdd(&cursor[d], 1);
        edges[pos] = make_int2(s, __float_as_int(nrm));
    }
}

// ============ aggregation: one wave per node, 4-edge batched gather ============
__global__ void agg_kernel(const int* __restrict__ row_ptr, const int2* __restrict__ edges,
                           const float* __restrict__ hw, const float* __restrict__ dis,
                           const float* __restrict__ b, float* __restrict__ out, int n) {
    int wid = (blockIdx.x * blockDim.x + threadIdx.x) >> 6;
    if (wid >= n) return;
    int lane = threadIdx.x & 63;
    int beg = row_ptr[wid], end = row_ptr[wid + 1];
    float di = dis[wid];
    float acc = hw[(size_t)wid * 64 + lane] * di * di;   // self-loop term
    int e = beg;
    for (; e + 4 <= end; e += 4) {
        int2 p0 = edges[e + 0];
        int2 p1 = edges[e + 1];
        int2 p2 = edges[e + 2];
        int2 p3 = edges[e + 3];
        float v0 = hw[(size_t)p0.x * 64 + lane];
        float v1 = hw[(size_t)p1.x * 64 + lane];
        float v2 = hw[(size_t)p2.x * 64 + lane];
        float v3 = hw[(size_t)p3.x * 64 + lane];
        acc = fmaf(v0, __int_as_float(p0.y), acc);
        acc = fmaf(v1, __int_as_float(p1.y), acc);
        acc = fmaf(v2, __int_as_float(p2.y), acc);
        acc = fmaf(v3, __int_as_float(p3.y), acc);
    }
    for (; e < end; e++) {
        int2 pr = edges[e];
        acc = fmaf(hw[(size_t)pr.x * 64 + lane], __int_as_float(pr.y), acc);
    }
    float v = acc + b[lane];
    out[(size_t)wid * 64 + lane] = v > 0.f ? v : 0.f;
}

// ============ GEMM: C[n,64] = A[n,K] @ W[K,64] ============
// Block: 64 rows x 64 cols, 256 threads. A-tile staged coalesced into LDS
// (float4, 1KB per wave-instr). Compute: thread (col, ty) owns 16 rows x 1 col;
// A-reads are full-wave broadcast ds_read_b128 (conflict-free), W-reads b32 2-way (free).
template <int K>
__global__ __launch_bounds__(256) void gemm_tile(const float* __restrict__ A,
                                                 const float* __restrict__ W,
                                                 float* __restrict__ C, int n) {
    __shared__ float sA[64 * K];
    __shared__ float sW[K * 64];
    const int tid = threadIdx.x;
    const int row0 = blockIdx.x * 64;
    const int rows = min(64, n - row0);

    // stage W: K*16 float4, coalesced
    const float4* W4 = (const float4*)W;
    float4* sW4 = (float4*)sW;
    for (int i = tid; i < K * 16; i += 256) sW4[i] = W4[i];
    // stage A tile: rows*K/4 float4, coalesced
    const float4* A4 = (const float4*)(A + (size_t)row0 * K);
    float4* sA4 = (float4*)sA;
    const int nElem = rows * (K / 4);
    for (int i = tid; i < nElem; i += 256) sA4[i] = A4[i];
    __syncthreads();

    const int col = tid & 63;
    const int ty  = tid >> 6;        // rows ty + 4*r, r = 0..15
    float acc[16];
#pragma unroll
    for (int r = 0; r < 16; r++) acc[r] = 0.f;

    for (int k = 0; k < K; k += 4) {
        float w0 = sW[(k + 0) * 64 + col];
        float w1 = sW[(k + 1) * 64 + col];
        float w2 = sW[(k + 2) * 64 + col];
        float w3 = sW[(k + 3) * 64 + col];
#pragma unroll
        for (int r = 0; r < 16; r++) {
            const float4 a = *(const float4*)&sA[(ty + 4 * r) * K + k];  // wave-broadcast
            acc[r] = fmaf(a.x, w0, acc[r]);
            acc[r] = fmaf(a.y, w1, acc[r]);
            acc[r] = fmaf(a.z, w2, acc[r]);
            acc[r] = fmaf(a.w, w3, acc[r]);
        }
    }
#pragma unroll
    for (int r = 0; r < 16; r++) {
        int row = ty + 4 * r;
        if (row < rows) C[(size_t)(row0 + row) * 64 + col] = acc[r];
    }
}

// ================= fallback (atomic path, small ws) =================
__global__ void fill_kernel(float* __restrict__ p, float v, int n) {
    int i = blockIdx.x * blockDim.x + threadIdx.x;
    if (i < n) p[i] = v;
}
__global__ void degree_kernel(const int* __restrict__ ei, float* __restrict__ deg, int E) {
    int stride = gridDim.x * blockDim.x;
    for (int e = blockIdx.x * blockDim.x + threadIdx.x; e < E; e += stride)
        atomicAdd(&deg[ei[E + e]], 1.0f);
}
__global__ void rsqrt_kernel(float* __restrict__ deg, int n) {
    int i = blockIdx.x * blockDim.x + threadIdx.x;
    if (i < n) deg[i] = rsqrtf(deg[i]);
}
__global__ void scatter_kernel(const int* __restrict__ ei, const float* __restrict__ hw,
                               const float* __restrict__ dis, float* __restrict__ agg, int E) {
    int gtid = blockIdx.x * blockDim.x + threadIdx.x;
    int wave = gtid >> 6, lane = threadIdx.x & 63;
    int nwaves = (gridDim.x * blockDim.x) >> 6;
    for (int e = wave; e < E; e += nwaves) {
        int s = ei[e], d = ei[E + e];
        float v = hw[(size_t)s * 64 + lane] * dis[s] * dis[d];
        atomicAdd(&agg[(size_t)d * 64 + lane], v);
    }
}
__global__ void finalize_kernel(float* __restrict__ agg, const float* __restrict__ hw,
                                const float* __restrict__ dis, const float* __restrict__ b, int n) {
    int i = blockIdx.x * blockDim.x + threadIdx.x;
    if (i < n * 64) {
        int node = i >> 6, col = i & 63;
        float di = dis[node];
        float v = agg[i] + hw[i] * di * di + b[col];
        agg[i] = v > 0.0f ? v : 0.0f;
    }
}

extern "C" void kernel_launch(void* const* d_in, const int* in_sizes, int n_in,
                              void* d_out, int out_size, void* d_ws, size_t ws_size,
                              hipStream_t stream) {
    const float* x  = (const float*)d_in[0];
    const int*   ei = (const int*)d_in[1];   // int32 [2, E] flat
    const float* W1 = (const float*)d_in[2];
    const float* b1 = (const float*)d_in[3];
    const float* W2 = (const float*)d_in[4];
    const float* b2 = (const float*)d_in[5];
    float* out = (float*)d_out;

    const int N = NN, E = NE;
    char* ws = (char*)d_ws;
    const int gemmGrid = (N + 63) / 64;

    if (ws_size >= 38200000u) {
        // ---- CSR path ----
        int*   cnt     = (int*)ws;                       // 0 .. 512K
        int*   row_ptr = (int*)(ws + (1u << 19));        // 512K .. 1M
        int*   cursor  = (int*)(ws + (2u << 19));        // 1M .. 1.5M
        float* dis     = (float*)(ws + (3u << 19));      // 1.5M .. 2M
        int2*  edges   = (int2*)(ws + (4u << 19));       // 2M .. 11.6M (9.6MB)
        float* bufA    = (float*)(ws + 12582912u);       // 12M .. 37.6M
        int*   blkSum  = cursor + ((NN + 127) & ~127) + 256;  // tail of cursor region

        const int nblk = (N + 1023) / 1024;  // 98

        hipMemsetAsync(cnt, 0, (N + 1) * sizeof(int), stream);
        count_kernel<<<2048, 256, 0, stream>>>(ei, cnt, E);
        dis_kernel<<<(N + 255) / 256, 256, 0, stream>>>(cnt, dis, N);
        scan_phase1<<<nblk, 256, 0, stream>>>(cnt, blkSum, N);
        scan_phase2<<<1, 128, 0, stream>>>(blkSum, row_ptr, nblk, N);
        scan_phase3<<<nblk, 256, 0, stream>>>(cnt, blkSum, row_ptr, cursor, N);
        fill_csr<<<2048, 256, 0, stream>>>(ei, dis, cursor, edges, E);

        // layer 1: hw1 -> bufA; h -> out
        gemm_tile<128><<<gemmGrid, 256, 0, stream>>>(x, W1, bufA, N);
        agg_kernel<<<(N * 64 + 255) / 256, 256, 0, stream>>>(row_ptr, edges, bufA, dis, b1, out, N);
        // layer 2: hw2 -> bufA; out final
        gemm_tile<64><<<gemmGrid, 256, 0, stream>>>(out, W2, bufA, N);
        agg_kernel<<<(N * 64 + 255) / 256, 256, 0, stream>>>(row_ptr, edges, bufA, dis, b2, out, N);
    } else {
        // ---- fallback: atomic path ----
        float* dis  = (float*)ws;
        float* bufA = (float*)(ws + (1 << 19));
        const size_t featBytes = (size_t)N * 64 * sizeof(float);

        fill_kernel<<<(N + 255) / 256, 256, 0, stream>>>(dis, 1.0f, N);
        degree_kernel<<<2048, 256, 0, stream>>>(ei, dis, E);
        rsqrt_kernel<<<(N + 255) / 256, 256, 0, stream>>>(dis, N);

        gemm_tile<128><<<gemmGrid, 256, 0, stream>>>(x, W1, bufA, N);
        hipMemsetAsync(out, 0, featBytes, stream);
        scatter_kernel<<<2048, 256, 0, stream>>>(ei, bufA, dis, out, E);
        finalize_kernel<<<(N * 64 + 255) / 256, 256, 0, stream>>>(out, bufA, dis, b1, N);

        gemm_tile<64><<<gemmGrid, 256, 0, stream>>>(out, W2, bufA, N);
        hipMemsetAsync(out, 0, featBytes, stream);
        scatter_kernel<<<2048, 256, 0, stream>>>(ei, bufA, dis, out, E);
        finalize_kernel<<<(N * 64 + 255) / 256, 256, 0, stream>>>(out, bufA, dis, b2, N);
    }
}

// Round 6
// 333.423 us; speedup vs baseline: 2.4484x; 1.0277x over previous
//
#include <hip/hip_runtime.h>
#include <hip/hip_fp16.h>
#include <cstdint>
#include <cstddef>

#define NN 100000
#define NE 1200000

// ================= CSR build =================
__global__ void count_kernel(const int* __restrict__ ei, int* __restrict__ cnt, int E) {
    int stride = gridDim.x * blockDim.x;
    for (int e = blockIdx.x * blockDim.x + threadIdx.x; e < E; e += stride)
        atomicAdd(&cnt[ei[E + e]], 1);
}

// ---- 3-phase multi-block exclusive scan; phase1 also computes dis = rsqrt(cnt+1) ----
__global__ void scan_phase1(const int* __restrict__ cnt, int* __restrict__ blkSum,
                            float* __restrict__ dis, int n) {
    __shared__ int red[256];
    int base = blockIdx.x * 1024, t = threadIdx.x;
    int s = 0;
#pragma unroll
    for (int j = 0; j < 4; j++) {
        int i = base + t * 4 + j;
        if (i < n) {
            int c = cnt[i];
            s += c;
            dis[i] = rsqrtf((float)c + 1.0f);   // +1 self-loop
        }
    }
    red[t] = s;
    __syncthreads();
    for (int off = 128; off > 0; off >>= 1) {
        if (t < off) red[t] += red[t + off];
        __syncthreads();
    }
    if (t == 0) blkSum[blockIdx.x] = red[0];
}

__global__ void scan_phase2(int* __restrict__ blkSum, int* __restrict__ row_ptr, int nblk, int n) {
    __shared__ int sh[128];
    int t = threadIdx.x;
    int v = (t < nblk) ? blkSum[t] : 0;
    sh[t] = v;
    __syncthreads();
    for (int off = 1; off < 128; off <<= 1) {
        int u = (t >= off) ? sh[t - off] : 0;
        __syncthreads();
        sh[t] += u;
        __syncthreads();
    }
    if (t < nblk) blkSum[t] = (t == 0) ? 0 : sh[t - 1];
    if (t == 0) row_ptr[n] = sh[127];
}

__global__ void scan_phase3(const int* __restrict__ cnt, const int* __restrict__ blkSum,
                            int* __restrict__ row_ptr, int* __restrict__ cursor, int n) {
    __shared__ int sh[256];
    int base = blockIdx.x * 1024, t = threadIdx.x;
    int idx = base + t * 4;
    int c[4];
    int s = 0;
#pragma unroll
    for (int j = 0; j < 4; j++) {
        int i = idx + j;
        c[j] = (i < n) ? cnt[i] : 0;
        s += c[j];
    }
    sh[t] = s;
    __syncthreads();
    for (int off = 1; off < 256; off <<= 1) {
        int u = (t >= off) ? sh[t - off] : 0;
        __syncthreads();
        sh[t] += u;
        __syncthreads();
    }
    int excl = blkSum[blockIdx.x] + ((t == 0) ? 0 : sh[t - 1]);
#pragma unroll
    for (int j = 0; j < 4; j++) {
        int i = idx + j;
        if (i < n) { row_ptr[i] = excl; cursor[i] = excl; }
        excl += c[j];
    }
}

__global__ void fill_csr(const int* __restrict__ ei, const float* __restrict__ dis,
                         int* __restrict__ cursor, int2* __restrict__ edges, int E) {
    int stride = gridDim.x * blockDim.x;
    for (int e = blockIdx.x * blockDim.x + threadIdx.x; e < E; e += stride) {
        int s = ei[e], d = ei[E + e];
        float nrm = dis[s] * dis[d];
        int pos = atomicAdd(&cursor[d], 1);
        edges[pos] = make_int2(s, __float_as_int(nrm));
    }
}

// ============ aggregation: one wave per node, 4-edge batched fp16 gather ============
__global__ void agg_kernel(const int* __restrict__ row_ptr, const int2* __restrict__ edges,
                           const __half* __restrict__ hw, const float* __restrict__ dis,
                           const float* __restrict__ b, float* __restrict__ out, int n) {
    int wid = (blockIdx.x * blockDim.x + threadIdx.x) >> 6;
    if (wid >= n) return;
    int lane = threadIdx.x & 63;
    int beg = row_ptr[wid], end = row_ptr[wid + 1];
    float di = dis[wid];
    float acc = __half2float(hw[(size_t)wid * 64 + lane]) * di * di;   // self-loop term
    int e = beg;
    for (; e + 4 <= end; e += 4) {
        int2 p0 = edges[e + 0];
        int2 p1 = edges[e + 1];
        int2 p2 = edges[e + 2];
        int2 p3 = edges[e + 3];
        __half v0 = hw[(size_t)p0.x * 64 + lane];
        __half v1 = hw[(size_t)p1.x * 64 + lane];
        __half v2 = hw[(size_t)p2.x * 64 + lane];
        __half v3 = hw[(size_t)p3.x * 64 + lane];
        acc = fmaf(__half2float(v0), __int_as_float(p0.y), acc);
        acc = fmaf(__half2float(v1), __int_as_float(p1.y), acc);
        acc = fmaf(__half2float(v2), __int_as_float(p2.y), acc);
        acc = fmaf(__half2float(v3), __int_as_float(p3.y), acc);
    }
    for (; e < end; e++) {
        int2 pr = edges[e];
        acc = fmaf(__half2float(hw[(size_t)pr.x * 64 + lane]), __int_as_float(pr.y), acc);
    }
    float v = acc + b[lane];
    out[(size_t)wid * 64 + lane] = v > 0.f ? v : 0.f;
}

// ============ GEMM: C[n,64] = A[n,K] @ W[K,64], fp16 output ============
template <int K>
__global__ __launch_bounds__(256) void gemm_tile_h(const float* __restrict__ A,
                                                   const float* __restrict__ W,
                                                   __half* __restrict__ C, int n) {
    __shared__ float sA[64 * K];
    __shared__ float sW[K * 64];
    const int tid = threadIdx.x;
    const int row0 = blockIdx.x * 64;
    const int rows = min(64, n - row0);

    const float4* W4 = (const float4*)W;
    float4* sW4 = (float4*)sW;
    for (int i = tid; i < K * 16; i += 256) sW4[i] = W4[i];
    const float4* A4 = (const float4*)(A + (size_t)row0 * K);
    float4* sA4 = (float4*)sA;
    const int nElem = rows * (K / 4);
    for (int i = tid; i < nElem; i += 256) sA4[i] = A4[i];
    __syncthreads();

    const int col = tid & 63;
    const int ty  = tid >> 6;
    float acc[16];
#pragma unroll
    for (int r = 0; r < 16; r++) acc[r] = 0.f;

    for (int k = 0; k < K; k += 4) {
        float w0 = sW[(k + 0) * 64 + col];
        float w1 = sW[(k + 1) * 64 + col];
        float w2 = sW[(k + 2) * 64 + col];
        float w3 = sW[(k + 3) * 64 + col];
#pragma unroll
        for (int r = 0; r < 16; r++) {
            const float4 a = *(const float4*)&sA[(ty + 4 * r) * K + k];  // wave-broadcast
            acc[r] = fmaf(a.x, w0, acc[r]);
            acc[r] = fmaf(a.y, w1, acc[r]);
            acc[r] = fmaf(a.z, w2, acc[r]);
            acc[r] = fmaf(a.w, w3, acc[r]);
        }
    }
#pragma unroll
    for (int r = 0; r < 16; r++) {
        int row = ty + 4 * r;
        if (row < rows) C[(size_t)(row0 + row) * 64 + col] = __float2half(acc[r]);
    }
}

// fp32-output variant (fallback path)
template <int K>
__global__ __launch_bounds__(256) void gemm_tile(const float* __restrict__ A,
                                                 const float* __restrict__ W,
                                                 float* __restrict__ C, int n) {
    __shared__ float sA[64 * K];
    __shared__ float sW[K * 64];
    const int tid = threadIdx.x;
    const int row0 = blockIdx.x * 64;
    const int rows = min(64, n - row0);
    const float4* W4 = (const float4*)W;
    float4* sW4 = (float4*)sW;
    for (int i = tid; i < K * 16; i += 256) sW4[i] = W4[i];
    const float4* A4 = (const float4*)(A + (size_t)row0 * K);
    float4* sA4 = (float4*)sA;
    const int nElem = rows * (K / 4);
    for (int i = tid; i < nElem; i += 256) sA4[i] = A4[i];
    __syncthreads();
    const int col = tid & 63;
    const int ty  = tid >> 6;
    float acc[16];
#pragma unroll
    for (int r = 0; r < 16; r++) acc[r] = 0.f;
    for (int k = 0; k < K; k += 4) {
        float w0 = sW[(k + 0) * 64 + col];
        float w1 = sW[(k + 1) * 64 + col];
        float w2 = sW[(k + 2) * 64 + col];
        float w3 = sW[(k + 3) * 64 + col];
#pragma unroll
        for (int r = 0; r < 16; r++) {
            const float4 a = *(const float4*)&sA[(ty + 4 * r) * K + k];
            acc[r] = fmaf(a.x, w0, acc[r]);
            acc[r] = fmaf(a.y, w1, acc[r]);
            acc[r] = fmaf(a.z, w2, acc[r]);
            acc[r] = fmaf(a.w, w3, acc[r]);
        }
    }
#pragma unroll
    for (int r = 0; r < 16; r++) {
        int row = ty + 4 * r;
        if (row < rows) C[(size_t)(row0 + row) * 64 + col] = acc[r];
    }
}

// ================= fallback (atomic path, small ws) =================
__global__ void fill_kernel(float* __restrict__ p, float v, int n) {
    int i = blockIdx.x * blockDim.x + threadIdx.x;
    if (i < n) p[i] = v;
}
__global__ void degree_kernel(const int* __restrict__ ei, float* __restrict__ deg, int E) {
    int stride = gridDim.x * blockDim.x;
    for (int e = blockIdx.x * blockDim.x + threadIdx.x; e < E; e += stride)
        atomicAdd(&deg[ei[E + e]], 1.0f);
}
__global__ void rsqrt_kernel(float* __restrict__ deg, int n) {
    int i = blockIdx.x * blockDim.x + threadIdx.x;
    if (i < n) deg[i] = rsqrtf(deg[i]);
}
__global__ void scatter_kernel(const int* __restrict__ ei, const float* __restrict__ hw,
                               const float* __restrict__ dis, float* __restrict__ agg, int E) {
    int gtid = blockIdx.x * blockDim.x + threadIdx.x;
    int wave = gtid >> 6, lane = threadIdx.x & 63;
    int nwaves = (gridDim.x * blockDim.x) >> 6;
    for (int e = wave; e < E; e += nwaves) {
        int s = ei[e], d = ei[E + e];
        float v = hw[(size_t)s * 64 + lane] * dis[s] * dis[d];
        atomicAdd(&agg[(size_t)d * 64 + lane], v);
    }
}
__global__ void finalize_kernel(float* __restrict__ agg, const float* __restrict__ hw,
                                const float* __restrict__ dis, const float* __restrict__ b, int n) {
    int i = blockIdx.x * blockDim.x + threadIdx.x;
    if (i < n * 64) {
        int node = i >> 6, col = i & 63;
        float di = dis[node];
        float v = agg[i] + hw[i] * di * di + b[col];
        agg[i] = v > 0.0f ? v : 0.0f;
    }
}

extern "C" void kernel_launch(void* const* d_in, const int* in_sizes, int n_in,
                              void* d_out, int out_size, void* d_ws, size_t ws_size,
                              hipStream_t stream) {
    const float* x  = (const float*)d_in[0];
    const int*   ei = (const int*)d_in[1];   // int32 [2, E] flat
    const float* W1 = (const float*)d_in[2];
    const float* b1 = (const float*)d_in[3];
    const float* W2 = (const float*)d_in[4];
    const float* b2 = (const float*)d_in[5];
    float* out = (float*)d_out;

    const int N = NN, E = NE;
    char* ws = (char*)d_ws;
    const int gemmGrid = (N + 63) / 64;

    if (ws_size >= 38200000u) {
        // ---- CSR path ----
        int*    cnt     = (int*)ws;                       // 0 .. 512K
        int*    row_ptr = (int*)(ws + (1u << 19));        // 512K .. 1M
        int*    cursor  = (int*)(ws + (2u << 19));        // 1M .. 1.5M
        float*  dis     = (float*)(ws + (3u << 19));      // 1.5M .. 2M
        int2*   edges   = (int2*)(ws + (4u << 19));       // 2M .. 11.6M (9.6MB)
        __half* hwa     = (__half*)(ws + 12582912u);      // 12M .. 24.8M (12.8MB fp16)
        int*    blkSum  = cursor + ((NN + 127) & ~127) + 256;  // tail of cursor region

        const int nblk = (N + 1023) / 1024;  // 98

        hipMemsetAsync(cnt, 0, (N + 1) * sizeof(int), stream);
        count_kernel<<<2048, 256, 0, stream>>>(ei, cnt, E);
        scan_phase1<<<nblk, 256, 0, stream>>>(cnt, blkSum, dis, N);
        scan_phase2<<<1, 128, 0, stream>>>(blkSum, row_ptr, nblk, N);
        scan_phase3<<<nblk, 256, 0, stream>>>(cnt, blkSum, row_ptr, cursor, N);
        fill_csr<<<2048, 256, 0, stream>>>(ei, dis, cursor, edges, E);

        // layer 1: hw1(fp16) -> hwa; h -> out
        gemm_tile_h<128><<<gemmGrid, 256, 0, stream>>>(x, W1, hwa, N);
        agg_kernel<<<(N * 64 + 255) / 256, 256, 0, stream>>>(row_ptr, edges, hwa, dis, b1, out, N);
        // layer 2: hw2(fp16) -> hwa; out final
        gemm_tile_h<64><<<gemmGrid, 256, 0, stream>>>(out, W2, hwa, N);
        agg_kernel<<<(N * 64 + 255) / 256, 256, 0, stream>>>(row_ptr, edges, hwa, dis, b2, out, N);
    } else {
        // ---- fallback: atomic path (fp32 throughout) ----
        float* dis  = (float*)ws;
        float* bufA = (float*)(ws + (1 << 19));
        const size_t featBytes = (size_t)N * 64 * sizeof(float);

        fill_kernel<<<(N + 255) / 256, 256, 0, stream>>>(dis, 1.0f, N);
        degree_kernel<<<2048, 256, 0, stream>>>(ei, dis, E);
        rsqrt_kernel<<<(N + 255) / 256, 256, 0, stream>>>(dis, N);

        gemm_tile<128><<<gemmGrid, 256, 0, stream>>>(x, W1, bufA, N);
        hipMemsetAsync(out, 0, featBytes, stream);
        scatter_kernel<<<2048, 256, 0, stream>>>(ei, bufA, dis, out, E);
        finalize_kernel<<<(N * 64 + 255) / 256, 256, 0, stream>>>(out, bufA, dis, b1, N);

        gemm_tile<64><<<gemmGrid, 256, 0, stream>>>(out, W2, bufA, N);
        hipMemsetAsync(out, 0, featBytes, stream);
        scatter_kernel<<<2048, 256, 0, stream>>>(ei, bufA, dis, out, E);
        finalize_kernel<<<(N * 64 + 255) / 256, 256, 0, stream>>>(out, bufA, dis, b2, N);
    }
}

// Round 7
// 266.053 us; speedup vs baseline: 3.0684x; 1.2532x over previous
//
#include <hip/hip_runtime.h>
#include <hip/hip_fp16.h>
#include <cstdint>
#include <cstddef>

#define NN 100000
#define NE 1200000

// ================= CSR build =================
// XCD-affine count: block bid handles dst range (bid&7) only; consecutive blocks
// round-robin XCDs on MI355X, so each range's cnt region stays in ONE XCD's L2.
__global__ void count_xcd(const int* __restrict__ ei, int* __restrict__ cnt,
                          int E, int nPerRange) {
    int r = blockIdx.x & 7;
    int grp = blockIdx.x >> 3;
    int nGrp = gridDim.x >> 3;
    int lo = r * nPerRange, hi = lo + nPerRange;
    for (int e = grp * blockDim.x + threadIdx.x; e < E; e += nGrp * blockDim.x) {
        int d = ei[E + e];
        if (d >= lo && d < hi) atomicAdd(&cnt[d], 1);
    }
}

// ---- 3-phase multi-block exclusive scan; phase1 also computes dis = rsqrt(cnt+1) ----
__global__ void scan_phase1(const int* __restrict__ cnt, int* __restrict__ blkSum,
                            float* __restrict__ dis, int n) {
    __shared__ int red[256];
    int base = blockIdx.x * 1024, t = threadIdx.x;
    int s = 0;
#pragma unroll
    for (int j = 0; j < 4; j++) {
        int i = base + t * 4 + j;
        if (i < n) {
            int c = cnt[i];
            s += c;
            dis[i] = rsqrtf((float)c + 1.0f);   // +1 self-loop
        }
    }
    red[t] = s;
    __syncthreads();
    for (int off = 128; off > 0; off >>= 1) {
        if (t < off) red[t] += red[t + off];
        __syncthreads();
    }
    if (t == 0) blkSum[blockIdx.x] = red[0];
}

__global__ void scan_phase2(int* __restrict__ blkSum, int* __restrict__ row_ptr, int nblk, int n) {
    __shared__ int sh[128];
    int t = threadIdx.x;
    int v = (t < nblk) ? blkSum[t] : 0;
    sh[t] = v;
    __syncthreads();
    for (int off = 1; off < 128; off <<= 1) {
        int u = (t >= off) ? sh[t - off] : 0;
        __syncthreads();
        sh[t] += u;
        __syncthreads();
    }
    if (t < nblk) blkSum[t] = (t == 0) ? 0 : sh[t - 1];
    if (t == 0) row_ptr[n] = sh[127];
}

__global__ void scan_phase3(const int* __restrict__ cnt, const int* __restrict__ blkSum,
                            int* __restrict__ row_ptr, int* __restrict__ cursor, int n) {
    __shared__ int sh[256];
    int base = blockIdx.x * 1024, t = threadIdx.x;
    int idx = base + t * 4;
    int c[4];
    int s = 0;
#pragma unroll
    for (int j = 0; j < 4; j++) {
        int i = idx + j;
        c[j] = (i < n) ? cnt[i] : 0;
        s += c[j];
    }
    sh[t] = s;
    __syncthreads();
    for (int off = 1; off < 256; off <<= 1) {
        int u = (t >= off) ? sh[t - off] : 0;
        __syncthreads();
        sh[t] += u;
        __syncthreads();
    }
    int excl = blkSum[blockIdx.x] + ((t == 0) ? 0 : sh[t - 1]);
#pragma unroll
    for (int j = 0; j < 4; j++) {
        int i = idx + j;
        if (i < n) { row_ptr[i] = excl; cursor[i] = excl; }
        excl += c[j];
    }
}

// XCD-affine fill: same range trick -> a CSR output region's lines accumulate
// ~8 records inside one XCD's L2 before eviction (write 78MB -> ~12MB).
__global__ void fill_csr_xcd(const int* __restrict__ ei, const float* __restrict__ dis,
                             int* __restrict__ cursor, int2* __restrict__ edges,
                             int E, int nPerRange) {
    int r = blockIdx.x & 7;
    int grp = blockIdx.x >> 3;
    int nGrp = gridDim.x >> 3;
    int lo = r * nPerRange, hi = lo + nPerRange;
    for (int e = grp * blockDim.x + threadIdx.x; e < E; e += nGrp * blockDim.x) {
        int d = ei[E + e];
        if (d >= lo && d < hi) {
            int s = ei[e];
            float nrm = dis[s] * dis[d];
            int pos = atomicAdd(&cursor[d], 1);
            edges[pos] = make_int2(s, __float_as_int(nrm));
        }
    }
}

// ============ aggregation: 4 nodes per wave (16 lanes each, 4 feats/lane) ============
#define ACC4(q, wbits)                                            \
    {                                                             \
        float w_ = __int_as_float(wbits);                         \
        __half2 h01_ = *(__half2*)&(q).x;                         \
        __half2 h23_ = *(__half2*)&(q).y;                         \
        float2 f01_ = __half22float2(h01_);                       \
        float2 f23_ = __half22float2(h23_);                       \
        acc0 = fmaf(f01_.x, w_, acc0);                            \
        acc1 = fmaf(f01_.y, w_, acc1);                            \
        acc2 = fmaf(f23_.x, w_, acc2);                            \
        acc3 = fmaf(f23_.y, w_, acc3);                            \
    }

__global__ void agg_kernel4(const int* __restrict__ row_ptr, const int2* __restrict__ edges,
                            const __half* __restrict__ hw, const float* __restrict__ dis,
                            const float* __restrict__ b, float* __restrict__ out, int n) {
    int gtid = blockIdx.x * blockDim.x + threadIdx.x;
    int wave = gtid >> 6;
    int lane = threadIdx.x & 63;
    int seg = lane >> 4;          // 0..3 : node within wave
    int sub = lane & 15;          // feature quad: features sub*4 .. sub*4+3
    int node = wave * 4 + seg;
    if (node >= n) return;

    const uint2* hwq = (const uint2*)hw;   // one row = 16 uint2 (64 fp16)
    int beg = row_ptr[node], end = row_ptr[node + 1];
    float di = dis[node];

    // self-loop term
    uint2 qs = hwq[(size_t)node * 16 + sub];
    float acc0 = 0.f, acc1 = 0.f, acc2 = 0.f, acc3 = 0.f;
    ACC4(qs, __float_as_int(di * di));

    int e = beg;
    for (; e + 4 <= end; e += 4) {
        int2 p0 = edges[e + 0];
        int2 p1 = edges[e + 1];
        int2 p2 = edges[e + 2];
        int2 p3 = edges[e + 3];
        uint2 q0 = hwq[(size_t)p0.x * 16 + sub];
        uint2 q1 = hwq[(size_t)p1.x * 16 + sub];
        uint2 q2 = hwq[(size_t)p2.x * 16 + sub];
        uint2 q3 = hwq[(size_t)p3.x * 16 + sub];
        ACC4(q0, p0.y);
        ACC4(q1, p1.y);
        ACC4(q2, p2.y);
        ACC4(q3, p3.y);
    }
    for (; e < end; e++) {
        int2 p = edges[e];
        uint2 q = hwq[(size_t)p.x * 16 + sub];
        ACC4(q, p.y);
    }

    const float4 bb = ((const float4*)b)[sub];
    float4 o;
    o.x = acc0 + bb.x; o.y = acc1 + bb.y; o.z = acc2 + bb.z; o.w = acc3 + bb.w;
    o.x = o.x > 0.f ? o.x : 0.f;
    o.y = o.y > 0.f ? o.y : 0.f;
    o.z = o.z > 0.f ? o.z : 0.f;
    o.w = o.w > 0.f ? o.w : 0.f;
    ((float4*)out)[(size_t)node * 16 + sub] = o;
}

// ============ GEMM: C[n,64] = A[n,K] @ W[K,64], fp16 output ============
template <int K>
__global__ __launch_bounds__(256) void gemm_tile_h(const float* __restrict__ A,
                                                   const float* __restrict__ W,
                                                   __half* __restrict__ C, int n) {
    __shared__ float sA[64 * K];
    __shared__ float sW[K * 64];
    const int tid = threadIdx.x;
    const int row0 = blockIdx.x * 64;
    const int rows = min(64, n - row0);

    const float4* W4 = (const float4*)W;
    float4* sW4 = (float4*)sW;
    for (int i = tid; i < K * 16; i += 256) sW4[i] = W4[i];
    const float4* A4 = (const float4*)(A + (size_t)row0 * K);
    float4* sA4 = (float4*)sA;
    const int nElem = rows * (K / 4);
    for (int i = tid; i < nElem; i += 256) sA4[i] = A4[i];
    __syncthreads();

    const int col = tid & 63;
    const int ty  = tid >> 6;
    float acc[16];
#pragma unroll
    for (int r = 0; r < 16; r++) acc[r] = 0.f;

    for (int k = 0; k < K; k += 4) {
        float w0 = sW[(k + 0) * 64 + col];
        float w1 = sW[(k + 1) * 64 + col];
        float w2 = sW[(k + 2) * 64 + col];
        float w3 = sW[(k + 3) * 64 + col];
#pragma unroll
        for (int r = 0; r < 16; r++) {
            const float4 a = *(const float4*)&sA[(ty + 4 * r) * K + k];  // wave-broadcast
            acc[r] = fmaf(a.x, w0, acc[r]);
            acc[r] = fmaf(a.y, w1, acc[r]);
            acc[r] = fmaf(a.z, w2, acc[r]);
            acc[r] = fmaf(a.w, w3, acc[r]);
        }
    }
#pragma unroll
    for (int r = 0; r < 16; r++) {
        int row = ty + 4 * r;
        if (row < rows) C[(size_t)(row0 + row) * 64 + col] = __float2half(acc[r]);
    }
}

// fp32-output variant (fallback path)
template <int K>
__global__ __launch_bounds__(256) void gemm_tile(const float* __restrict__ A,
                                                 const float* __restrict__ W,
                                                 float* __restrict__ C, int n) {
    __shared__ float sA[64 * K];
    __shared__ float sW[K * 64];
    const int tid = threadIdx.x;
    const int row0 = blockIdx.x * 64;
    const int rows = min(64, n - row0);
    const float4* W4 = (const float4*)W;
    float4* sW4 = (float4*)sW;
    for (int i = tid; i < K * 16; i += 256) sW4[i] = W4[i];
    const float4* A4 = (const float4*)(A + (size_t)row0 * K);
    float4* sA4 = (float4*)sA;
    const int nElem = rows * (K / 4);
    for (int i = tid; i < nElem; i += 256) sA4[i] = A4[i];
    __syncthreads();
    const int col = tid & 63;
    const int ty  = tid >> 6;
    float acc[16];
#pragma unroll
    for (int r = 0; r < 16; r++) acc[r] = 0.f;
    for (int k = 0; k < K; k += 4) {
        float w0 = sW[(k + 0) * 64 + col];
        float w1 = sW[(k + 1) * 64 + col];
        float w2 = sW[(k + 2) * 64 + col];
        float w3 = sW[(k + 3) * 64 + col];
#pragma unroll
        for (int r = 0; r < 16; r++) {
            const float4 a = *(const float4*)&sA[(ty + 4 * r) * K + k];
            acc[r] = fmaf(a.x, w0, acc[r]);
            acc[r] = fmaf(a.y, w1, acc[r]);
            acc[r] = fmaf(a.z, w2, acc[r]);
            acc[r] = fmaf(a.w, w3, acc[r]);
        }
    }
#pragma unroll
    for (int r = 0; r < 16; r++) {
        int row = ty + 4 * r;
        if (row < rows) C[(size_t)(row0 + row) * 64 + col] = acc[r];
    }
}

// ================= fallback (atomic path, small ws) =================
__global__ void fill_kernel(float* __restrict__ p, float v, int n) {
    int i = blockIdx.x * blockDim.x + threadIdx.x;
    if (i < n) p[i] = v;
}
__global__ void degree_kernel(const int* __restrict__ ei, float* __restrict__ deg, int E) {
    int stride = gridDim.x * blockDim.x;
    for (int e = blockIdx.x * blockDim.x + threadIdx.x; e < E; e += stride)
        atomicAdd(&deg[ei[E + e]], 1.0f);
}
__global__ void rsqrt_kernel(float* __restrict__ deg, int n) {
    int i = blockIdx.x * blockDim.x + threadIdx.x;
    if (i < n) deg[i] = rsqrtf(deg[i]);
}
__global__ void scatter_kernel(const int* __restrict__ ei, const float* __restrict__ hw,
                               const float* __restrict__ dis, float* __restrict__ agg, int E) {
    int gtid = blockIdx.x * blockDim.x + threadIdx.x;
    int wave = gtid >> 6, lane = threadIdx.x & 63;
    int nwaves = (gridDim.x * blockDim.x) >> 6;
    for (int e = wave; e < E; e += nwaves) {
        int s = ei[e], d = ei[E + e];
        float v = hw[(size_t)s * 64 + lane] * dis[s] * dis[d];
        atomicAdd(&agg[(size_t)d * 64 + lane], v);
    }
}
__global__ void finalize_kernel(float* __restrict__ agg, const float* __restrict__ hw,
                                const float* __restrict__ dis, const float* __restrict__ b, int n) {
    int i = blockIdx.x * blockDim.x + threadIdx.x;
    if (i < n * 64) {
        int node = i >> 6, col = i & 63;
        float di = dis[node];
        float v = agg[i] + hw[i] * di * di + b[col];
        agg[i] = v > 0.0f ? v : 0.0f;
    }
}

extern "C" void kernel_launch(void* const* d_in, const int* in_sizes, int n_in,
                              void* d_out, int out_size, void* d_ws, size_t ws_size,
                              hipStream_t stream) {
    const float* x  = (const float*)d_in[0];
    const int*   ei = (const int*)d_in[1];   // int32 [2, E] flat
    const float* W1 = (const float*)d_in[2];
    const float* b1 = (const float*)d_in[3];
    const float* W2 = (const float*)d_in[4];
    const float* b2 = (const float*)d_in[5];
    float* out = (float*)d_out;

    const int N = NN, E = NE;
    char* ws = (char*)d_ws;
    const int gemmGrid = (N + 63) / 64;
    const int nPerRange = (N + 7) / 8;   // 12500

    if (ws_size >= 38200000u) {
        // ---- CSR path ----
        int*    cnt     = (int*)ws;                       // 0 .. 512K
        int*    row_ptr = (int*)(ws + (1u << 19));        // 512K .. 1M
        int*    cursor  = (int*)(ws + (2u << 19));        // 1M .. 1.5M
        float*  dis     = (float*)(ws + (3u << 19));      // 1.5M .. 2M
        int2*   edges   = (int2*)(ws + (4u << 19));       // 2M .. 11.6M (9.6MB)
        __half* hwa     = (__half*)(ws + 12582912u);      // 12M .. 24.8M (12.8MB fp16)
        int*    blkSum  = cursor + ((NN + 127) & ~127) + 256;  // tail of cursor region

        const int nblk = (N + 1023) / 1024;  // 98

        hipMemsetAsync(cnt, 0, (N + 1) * sizeof(int), stream);
        count_xcd<<<2048, 256, 0, stream>>>(ei, cnt, E, nPerRange);
        scan_phase1<<<nblk, 256, 0, stream>>>(cnt, blkSum, dis, N);
        scan_phase2<<<1, 128, 0, stream>>>(blkSum, row_ptr, nblk, N);
        scan_phase3<<<nblk, 256, 0, stream>>>(cnt, blkSum, row_ptr, cursor, N);
        fill_csr_xcd<<<2048, 256, 0, stream>>>(ei, dis, cursor, edges, E, nPerRange);

        const int aggBlocks = ((N + 3) / 4 * 64 + 255) / 256;   // 4 nodes per wave
        // layer 1: hw1(fp16) -> hwa; h -> out
        gemm_tile_h<128><<<gemmGrid, 256, 0, stream>>>(x, W1, hwa, N);
        agg_kernel4<<<aggBlocks, 256, 0, stream>>>(row_ptr, edges, hwa, dis, b1, out, N);
        // layer 2: hw2(fp16) -> hwa; out final
        gemm_tile_h<64><<<gemmGrid, 256, 0, stream>>>(out, W2, hwa, N);
        agg_kernel4<<<aggBlocks, 256, 0, stream>>>(row_ptr, edges, hwa, dis, b2, out, N);
    } else {
        // ---- fallback: atomic path (fp32 throughout) ----
        float* dis  = (float*)ws;
        float* bufA = (float*)(ws + (1 << 19));
        const size_t featBytes = (size_t)N * 64 * sizeof(float);

        fill_kernel<<<(N + 255) / 256, 256, 0, stream>>>(dis, 1.0f, N);
        degree_kernel<<<2048, 256, 0, stream>>>(ei, dis, E);
        rsqrt_kernel<<<(N + 255) / 256, 256, 0, stream>>>(dis, N);

        gemm_tile<128><<<gemmGrid, 256, 0, stream>>>(x, W1, bufA, N);
        hipMemsetAsync(out, 0, featBytes, stream);
        scatter_kernel<<<2048, 256, 0, stream>>>(ei, bufA, dis, out, E);
        finalize_kernel<<<(N * 64 + 255) / 256, 256, 0, stream>>>(out, bufA, dis, b1, N);

        gemm_tile<64><<<gemmGrid, 256, 0, stream>>>(out, W2, bufA, N);
        hipMemsetAsync(out, 0, featBytes, stream);
        scatter_kernel<<<2048, 256, 0, stream>>>(ei, bufA, dis, out, E);
        finalize_kernel<<<(N * 64 + 255) / 256, 256, 0, stream>>>(out, bufA, dis, b2, N);
    }
}

// Round 8
// 259.716 us; speedup vs baseline: 3.1433x; 1.0244x over previous
//
#include <hip/hip_runtime.h>
#include <hip/hip_fp16.h>
#include <cstdint>
#include <cstddef>

#define NN 100000
#define NE 1200000

typedef _Float16 f16x8 __attribute__((ext_vector_type(8)));
typedef float f32x4 __attribute__((ext_vector_type(4)));

// ================= CSR build =================
__global__ void count_xcd(const int* __restrict__ ei, int* __restrict__ cnt,
                          int E, int nPerRange) {
    int r = blockIdx.x & 7;
    int grp = blockIdx.x >> 3;
    int nGrp = gridDim.x >> 3;
    int lo = r * nPerRange, hi = lo + nPerRange;
    for (int e = grp * blockDim.x + threadIdx.x; e < E; e += nGrp * blockDim.x) {
        int d = ei[E + e];
        if (d >= lo && d < hi) atomicAdd(&cnt[d], 1);
    }
}

// ---- 3-phase multi-block exclusive scan; phase1 also computes dis = rsqrt(cnt+1) ----
__global__ void scan_phase1(const int* __restrict__ cnt, int* __restrict__ blkSum,
                            float* __restrict__ dis, int n) {
    __shared__ int red[256];
    int base = blockIdx.x * 1024, t = threadIdx.x;
    int s = 0;
#pragma unroll
    for (int j = 0; j < 4; j++) {
        int i = base + t * 4 + j;
        if (i < n) {
            int c = cnt[i];
            s += c;
            dis[i] = rsqrtf((float)c + 1.0f);   // +1 self-loop
        }
    }
    red[t] = s;
    __syncthreads();
    for (int off = 128; off > 0; off >>= 1) {
        if (t < off) red[t] += red[t + off];
        __syncthreads();
    }
    if (t == 0) blkSum[blockIdx.x] = red[0];
}

__global__ void scan_phase2(int* __restrict__ blkSum, int* __restrict__ row_ptr, int nblk, int n) {
    __shared__ int sh[128];
    int t = threadIdx.x;
    int v = (t < nblk) ? blkSum[t] : 0;
    sh[t] = v;
    __syncthreads();
    for (int off = 1; off < 128; off <<= 1) {
        int u = (t >= off) ? sh[t - off] : 0;
        __syncthreads();
        sh[t] += u;
        __syncthreads();
    }
    if (t < nblk) blkSum[t] = (t == 0) ? 0 : sh[t - 1];
    if (t == 0) row_ptr[n] = sh[127];
}

__global__ void scan_phase3(const int* __restrict__ cnt, const int* __restrict__ blkSum,
                            int* __restrict__ row_ptr, int* __restrict__ cursor, int n) {
    __shared__ int sh[256];
    int base = blockIdx.x * 1024, t = threadIdx.x;
    int idx = base + t * 4;
    int c[4];
    int s = 0;
#pragma unroll
    for (int j = 0; j < 4; j++) {
        int i = idx + j;
        c[j] = (i < n) ? cnt[i] : 0;
        s += c[j];
    }
    sh[t] = s;
    __syncthreads();
    for (int off = 1; off < 256; off <<= 1) {
        int u = (t >= off) ? sh[t - off] : 0;
        __syncthreads();
        sh[t] += u;
        __syncthreads();
    }
    int excl = blkSum[blockIdx.x] + ((t == 0) ? 0 : sh[t - 1]);
#pragma unroll
    for (int j = 0; j < 4; j++) {
        int i = idx + j;
        if (i < n) { row_ptr[i] = excl; cursor[i] = excl; }
        excl += c[j];
    }
}

// Record writes via 64-bit atomicExch: atomics execute cache-side, so the
// 64B line accumulates ~8 records before writeback (plain 8B stores are
// write-miss no-allocate -> full line to HBM each, R7: WRITE_SIZE 73MB).
__global__ void fill_csr_xcd(const int* __restrict__ ei, const float* __restrict__ dis,
                             int* __restrict__ cursor, int2* __restrict__ edges,
                             int E, int nPerRange) {
    int r = blockIdx.x & 7;
    int grp = blockIdx.x >> 3;
    int nGrp = gridDim.x >> 3;
    int lo = r * nPerRange, hi = lo + nPerRange;
    for (int e = grp * blockDim.x + threadIdx.x; e < E; e += nGrp * blockDim.x) {
        int d = ei[E + e];
        if (d >= lo && d < hi) {
            int s = ei[e];
            float nrm = dis[s] * dis[d];
            int pos = atomicAdd(&cursor[d], 1);
            unsigned long long rec =
                ((unsigned long long)__float_as_uint(nrm) << 32) | (unsigned)s;
            atomicExch((unsigned long long*)(edges + pos), rec);
        }
    }
}

// ============ aggregation: 4 nodes per wave (16 lanes each, 4 feats/lane) ============
#define ACC4(q, wbits)                                            \
    {                                                             \
        float w_ = __int_as_float(wbits);                         \
        __half2 h01_ = *(__half2*)&(q).x;                         \
        __half2 h23_ = *(__half2*)&(q).y;                         \
        float2 f01_ = __half22float2(h01_);                       \
        float2 f23_ = __half22float2(h23_);                       \
        acc0 = fmaf(f01_.x, w_, acc0);                            \
        acc1 = fmaf(f01_.y, w_, acc1);                            \
        acc2 = fmaf(f23_.x, w_, acc2);                            \
        acc3 = fmaf(f23_.y, w_, acc3);                            \
    }

__global__ void agg_kernel4(const int* __restrict__ row_ptr, const int2* __restrict__ edges,
                            const __half* __restrict__ hw, const float* __restrict__ dis,
                            const float* __restrict__ b, float* __restrict__ out, int n) {
    int gtid = blockIdx.x * blockDim.x + threadIdx.x;
    int wave = gtid >> 6;
    int lane = threadIdx.x & 63;
    int seg = lane >> 4;          // 0..3 : node within wave
    int sub = lane & 15;          // feature quad: features sub*4 .. sub*4+3
    int node = wave * 4 + seg;
    if (node >= n) return;

    const uint2* hwq = (const uint2*)hw;   // one row = 16 uint2 (64 fp16)
    int beg = row_ptr[node], end = row_ptr[node + 1];
    float di = dis[node];

    uint2 qs = hwq[(size_t)node * 16 + sub];
    float acc0 = 0.f, acc1 = 0.f, acc2 = 0.f, acc3 = 0.f;
    ACC4(qs, __float_as_int(di * di));

    int e = beg;
    for (; e + 4 <= end; e += 4) {
        int2 p0 = edges[e + 0];
        int2 p1 = edges[e + 1];
        int2 p2 = edges[e + 2];
        int2 p3 = edges[e + 3];
        uint2 q0 = hwq[(size_t)p0.x * 16 + sub];
        uint2 q1 = hwq[(size_t)p1.x * 16 + sub];
        uint2 q2 = hwq[(size_t)p2.x * 16 + sub];
        uint2 q3 = hwq[(size_t)p3.x * 16 + sub];
        ACC4(q0, p0.y);
        ACC4(q1, p1.y);
        ACC4(q2, p2.y);
        ACC4(q3, p3.y);
    }
    for (; e < end; e++) {
        int2 p = edges[e];
        uint2 q = hwq[(size_t)p.x * 16 + sub];
        ACC4(q, p.y);
    }

    const float4 bb = ((const float4*)b)[sub];
    float4 o;
    o.x = acc0 + bb.x; o.y = acc1 + bb.y; o.z = acc2 + bb.z; o.w = acc3 + bb.w;
    o.x = o.x > 0.f ? o.x : 0.f;
    o.y = o.y > 0.f ? o.y : 0.f;
    o.z = o.z > 0.f ? o.z : 0.f;
    o.w = o.w > 0.f ? o.w : 0.f;
    ((float4*)out)[(size_t)node * 16 + sub] = o;
}

// ============ MFMA GEMM: C[n,64] = A[n,K] @ W[K,64], fp16 in / fp32 acc / fp16 out ====
// Block 256 thr = 4 waves, 64x64 tile. A,W converted fp32->fp16 during staging and
// stored in FRAGMENT order: lane-contiguous 16B -> conflict-free ds_read_b128.
// v_mfma_f32_16x16x32_f16: A lane l holds row=l&15, k=(l>>4)*8+j; B: col=l&15, same k.
// C/D: col=lane&15, row=(lane>>4)*4+reg (verified layout, dtype-independent).
template <int K>
__global__ __launch_bounds__(256) void gemm_mfma(const float* __restrict__ A,
                                                 const float* __restrict__ W,
                                                 __half* __restrict__ C, int n) {
    constexpr int KB = K / 32;
    __shared__ f16x8 sAf[4 * KB * 64];   // [rt][kb][lane]
    __shared__ f16x8 sWf[4 * KB * 64];   // [ct][kb][lane]
    const int tid = threadIdx.x;
    const int row0 = blockIdx.x * 64;

    // ---- stage A as MFMA A-fragments ----
    _Float16* sAh = (_Float16*)sAf;
    const float4* A4 = (const float4*)A;
#pragma unroll
    for (int it = 0; it < K / 16; ++it) {   // 64*(K/4) float4 / 256 threads
        int f = it * 256 + tid;
        int row = f / (K / 4);
        int kq = f % (K / 4);
        int k0 = kq * 4;
        float4 a;
        if (row0 + row < n) a = A4[(size_t)(row0 + row) * (K / 4) + kq];
        else { a.x = 0.f; a.y = 0.f; a.z = 0.f; a.w = 0.f; }
        int rt = row >> 4;
        int kb = k0 >> 5;
        int lane = (row & 15) | (((k0 >> 3) & 3) << 4);
        int base = ((rt * KB + kb) * 64 + lane) * 8 + (k0 & 7);
        sAh[base + 0] = (_Float16)a.x;
        sAh[base + 1] = (_Float16)a.y;
        sAh[base + 2] = (_Float16)a.z;
        sAh[base + 3] = (_Float16)a.w;
    }
    // ---- stage W as MFMA B-fragments (coalesced 4B loads, 2B LDS stores) ----
    _Float16* sWh = (_Float16*)sWf;
    {
        int nn = tid & 63;
        int ct = nn >> 4;
        int lbase = nn & 15;
        for (int k = tid >> 6; k < K; k += 4) {
            float w = W[(size_t)k * 64 + nn];
            int kb = k >> 5;
            int lane = lbase | (((k >> 3) & 3) << 4);
            sWh[((ct * KB + kb) * 64 + lane) * 8 + (k & 7)] = (_Float16)w;
        }
    }
    __syncthreads();

    const int wv = tid >> 6;     // wave id = col-tile
    const int lane = tid & 63;
    f32x4 acc[4];
#pragma unroll
    for (int rt = 0; rt < 4; ++rt) acc[rt] = (f32x4){0.f, 0.f, 0.f, 0.f};

#pragma unroll
    for (int kb = 0; kb < KB; ++kb) {
        f16x8 bf = sWf[(wv * KB + kb) * 64 + lane];
#pragma unroll
        for (int rt = 0; rt < 4; ++rt) {
            f16x8 af = sAf[(rt * KB + kb) * 64 + lane];
            acc[rt] = __builtin_amdgcn_mfma_f32_16x16x32_f16(af, bf, acc[rt], 0, 0, 0);
        }
    }

    int col = wv * 16 + (lane & 15);
    int rbase = (lane >> 4) * 4;
#pragma unroll
    for (int rt = 0; rt < 4; ++rt) {
#pragma unroll
        for (int r = 0; r < 4; ++r) {
            int row = row0 + rt * 16 + rbase + r;
            if (row < n) C[(size_t)row * 64 + col] = __float2half(acc[rt][r]);
        }
    }
}

// ================= fallback (atomic path, small ws) =================
__global__ void fill_kernel(float* __restrict__ p, float v, int n) {
    int i = blockIdx.x * blockDim.x + threadIdx.x;
    if (i < n) p[i] = v;
}
__global__ void degree_kernel(const int* __restrict__ ei, float* __restrict__ deg, int E) {
    int stride = gridDim.x * blockDim.x;
    for (int e = blockIdx.x * blockDim.x + threadIdx.x; e < E; e += stride)
        atomicAdd(&deg[ei[E + e]], 1.0f);
}
__global__ void rsqrt_kernel(float* __restrict__ deg, int n) {
    int i = blockIdx.x * blockDim.x + threadIdx.x;
    if (i < n) deg[i] = rsqrtf(deg[i]);
}
template <int K>
__global__ __launch_bounds__(256) void gemm_tile(const float* __restrict__ A,
                                                 const float* __restrict__ W,
                                                 float* __restrict__ C, int n) {
    __shared__ float sA[64 * K];
    __shared__ float sW[K * 64];
    const int tid = threadIdx.x;
    const int row0 = blockIdx.x * 64;
    const int rows = min(64, n - row0);
    const float4* W4 = (const float4*)W;
    float4* sW4 = (float4*)sW;
    for (int i = tid; i < K * 16; i += 256) sW4[i] = W4[i];
    const float4* A4 = (const float4*)(A + (size_t)row0 * K);
    float4* sA4 = (float4*)sA;
    const int nElem = rows * (K / 4);
    for (int i = tid; i < nElem; i += 256) sA4[i] = A4[i];
    __syncthreads();
    const int col = tid & 63;
    const int ty  = tid >> 6;
    float acc[16];
#pragma unroll
    for (int r = 0; r < 16; r++) acc[r] = 0.f;
    for (int k = 0; k < K; k += 4) {
        float w0 = sW[(k + 0) * 64 + col];
        float w1 = sW[(k + 1) * 64 + col];
        float w2 = sW[(k + 2) * 64 + col];
        float w3 = sW[(k + 3) * 64 + col];
#pragma unroll
        for (int r = 0; r < 16; r++) {
            const float4 a = *(const float4*)&sA[(ty + 4 * r) * K + k];
            acc[r] = fmaf(a.x, w0, acc[r]);
            acc[r] = fmaf(a.y, w1, acc[r]);
            acc[r] = fmaf(a.z, w2, acc[r]);
            acc[r] = fmaf(a.w, w3, acc[r]);
        }
    }
#pragma unroll
    for (int r = 0; r < 16; r++) {
        int row = ty + 4 * r;
        if (row < rows) C[(size_t)(row0 + row) * 64 + col] = acc[r];
    }
}
__global__ void scatter_kernel(const int* __restrict__ ei, const float* __restrict__ hw,
                               const float* __restrict__ dis, float* __restrict__ agg, int E) {
    int gtid = blockIdx.x * blockDim.x + threadIdx.x;
    int wave = gtid >> 6, lane = threadIdx.x & 63;
    int nwaves = (gridDim.x * blockDim.x) >> 6;
    for (int e = wave; e < E; e += nwaves) {
        int s = ei[e], d = ei[E + e];
        float v = hw[(size_t)s * 64 + lane] * dis[s] * dis[d];
        atomicAdd(&agg[(size_t)d * 64 + lane], v);
    }
}
__global__ void finalize_kernel(float* __restrict__ agg, const float* __restrict__ hw,
                                const float* __restrict__ dis, const float* __restrict__ b, int n) {
    int i = blockIdx.x * blockDim.x + threadIdx.x;
    if (i < n * 64) {
        int node = i >> 6, col = i & 63;
        float di = dis[node];
        float v = agg[i] + hw[i] * di * di + b[col];
        agg[i] = v > 0.0f ? v : 0.0f;
    }
}

extern "C" void kernel_launch(void* const* d_in, const int* in_sizes, int n_in,
                              void* d_out, int out_size, void* d_ws, size_t ws_size,
                              hipStream_t stream) {
    const float* x  = (const float*)d_in[0];
    const int*   ei = (const int*)d_in[1];   // int32 [2, E] flat
    const float* W1 = (const float*)d_in[2];
    const float* b1 = (const float*)d_in[3];
    const float* W2 = (const float*)d_in[4];
    const float* b2 = (const float*)d_in[5];
    float* out = (float*)d_out;

    const int N = NN, E = NE;
    char* ws = (char*)d_ws;
    const int gemmGrid = (N + 63) / 64;
    const int nPerRange = (N + 7) / 8;   // 12500

    if (ws_size >= 38200000u) {
        // ---- CSR path ----
        int*    cnt     = (int*)ws;                       // 0 .. 512K
        int*    row_ptr = (int*)(ws + (1u << 19));        // 512K .. 1M
        int*    cursor  = (int*)(ws + (2u << 19));        // 1M .. 1.5M
        float*  dis     = (float*)(ws + (3u << 19));      // 1.5M .. 2M
        int2*   edges   = (int2*)(ws + (4u << 19));       // 2M .. 11.6M (9.6MB)
        __half* hwa     = (__half*)(ws + 12582912u);      // 12M .. 24.8M (12.8MB fp16)
        int*    blkSum  = cursor + ((NN + 127) & ~127) + 256;  // tail of cursor region

        const int nblk = (N + 1023) / 1024;  // 98

        hipMemsetAsync(cnt, 0, (N + 1) * sizeof(int), stream);
        count_xcd<<<2048, 256, 0, stream>>>(ei, cnt, E, nPerRange);
        scan_phase1<<<nblk, 256, 0, stream>>>(cnt, blkSum, dis, N);
        scan_phase2<<<1, 128, 0, stream>>>(blkSum, row_ptr, nblk, N);
        scan_phase3<<<nblk, 256, 0, stream>>>(cnt, blkSum, row_ptr, cursor, N);
        fill_csr_xcd<<<2048, 256, 0, stream>>>(ei, dis, cursor, edges, E, nPerRange);

        const int aggBlocks = ((N + 3) / 4 * 64 + 255) / 256;   // 4 nodes per wave
        // layer 1: hw1(fp16) -> hwa; h -> out
        gemm_mfma<128><<<gemmGrid, 256, 0, stream>>>(x, W1, hwa, N);
        agg_kernel4<<<aggBlocks, 256, 0, stream>>>(row_ptr, edges, hwa, dis, b1, out, N);
        // layer 2: hw2(fp16) -> hwa; out final
        gemm_mfma<64><<<gemmGrid, 256, 0, stream>>>(out, W2, hwa, N);
        agg_kernel4<<<aggBlocks, 256, 0, stream>>>(row_ptr, edges, hwa, dis, b2, out, N);
    } else {
        // ---- fallback: atomic path (fp32 throughout) ----
        float* dis  = (float*)ws;
        float* bufA = (float*)(ws + (1 << 19));
        const size_t featBytes = (size_t)N * 64 * sizeof(float);

        fill_kernel<<<(N + 255) / 256, 256, 0, stream>>>(dis, 1.0f, N);
        degree_kernel<<<2048, 256, 0, stream>>>(ei, dis, E);
        rsqrt_kernel<<<(N + 255) / 256, 256, 0, stream>>>(dis, N);

        gemm_tile<128><<<gemmGrid, 256, 0, stream>>>(x, W1, bufA, N);
        hipMemsetAsync(out, 0, featBytes, stream);
        scatter_kernel<<<2048, 256, 0, stream>>>(ei, bufA, dis, out, E);
        finalize_kernel<<<(N * 64 + 255) / 256, 256, 0, stream>>>(out, bufA, dis, b1, N);

        gemm_tile<64><<<gemmGrid, 256, 0, stream>>>(out, W2, bufA, N);
        hipMemsetAsync(out, 0, featBytes, stream);
        scatter_kernel<<<2048, 256, 0, stream>>>(ei, bufA, dis, out, E);
        finalize_kernel<<<(N * 64 + 255) / 256, 256, 0, stream>>>(out, bufA, dis, b2, N);
    }
}